// Round 1
// 347.160 us; speedup vs baseline: 1.2464x; 1.2464x over previous
//
#include <hip/hip_runtime.h>

// Problem constants
#define BATCH 4096
#define CCH   22
#define TT    1001   // usable time samples (row length 1002; last elem = subject id)
#define TROW  1002
#define KOUT  40
#define KSZ   25
#define WOUT  977    // 1001 - 25 + 1
#define POOLW 100
#define NWIN  9
#define FEAT  360
#define NOUT  4

// Conv-MFMA tiling: 4 blocks along w with exclusive ownership
//   block bx computes w in [w0, w0+256), owns [w0, oend) for stats+pool
//   w0  = {0, 252, 500, 752}, oend = {252, 500, 752, 977}
#define WBLK  256
#define NWB   4
#define NBLK  (BATCH * NWB)    // 16384
//
// im2col-by-stride: LDS x-tile is [t][c] bf16 with row stride EXACTLY CSTG=24
// elements (48 B). Then the flattened reduction index f = j*24 + c is LINEAR
// in LDS (byte = w*48 + 2*f), so MFMA A-fragments are contiguous b128 reads
// that cross tap boundaries. K-steps: ceil(25*24/32) = 19 (vs 25 with per-tap
// C-padding to 32) -> -24% MFMA work. Pads (c in {22,23}, f >= 600) are
// neutralized by zeroed WEIGHTS; A may read arbitrary finite staged data.
#define CSTG  24               // padded channels (row = 48 B, 16B-aligned b128)
#define ROWB  48               // LDS row stride bytes
#define TSTG  288              // rows staged (need 281 = 256 + 25); 9 groups of 32
#define FKK   19               // MFMA K-steps of 32 over flattened (j,c)
#define KP    48               // k_out padded to 3 MFMA n-tiles
#define NLOC  4                // pool-window slots per block (incl. pseudo-windows >=9)

typedef __attribute__((ext_vector_type(8))) short short8;
typedef __attribute__((ext_vector_type(4))) float floatx4;

__device__ __forceinline__ unsigned short f2bf(float f) {
    unsigned u = __float_as_uint(f);
    u += 0x7fff + ((u >> 16) & 1);          // round-to-nearest-even
    return (unsigned short)(u >> 16);
}
// HW packed f32->bf16 RNE convert (same rounding as f2bf, 1 instr for 2 vals)
__device__ __forceinline__ unsigned cvt_pk_bf16(float a, float b) {
    unsigned r;
    asm("v_cvt_pk_bf16_f32 %0, %1, %2" : "=v"(r) : "v"(a), "v"(b));
    return r;
}
__device__ __forceinline__ float eluf(float v) {
    return v > 0.0f ? v : __expf(v) - 1.0f;
}

// Pack conv weights into MFMA B-operand layout over the flattened reduction:
// wp[kk][n=0..47][e=0..31] bf16, where f = kk*32+e, j = f/24, c = f%24.
__global__ __launch_bounds__(256) void pack_w_kernel(const float* __restrict__ cw,
                                                     unsigned short* __restrict__ wp) {
    int i = blockIdx.x * 256 + threadIdx.x;      // over FKK*KP*32 = 29184
    if (i >= FKK * KP * 32) return;
    int e = i & 31;
    int n = (i >> 5) % KP;
    int kk = i / (KP * 32);
    int f = kk * 32 + e;
    int j = f / CSTG, c = f - j * CSTG;
    float v = (n < KOUT && c < CCH && j < KSZ) ? cw[(n * CCH + c) * KSZ + j] : 0.0f;
    wp[i] = f2bf(v);
}

// Conv(bf16 MFMA) + bias + ELU + owned pool-window sums + owned BN partials.
// grid (NWB, BATCH), block 256 = 4 waves; wave wv owns 64 w's (4 m-tiles).
__global__ __launch_bounds__(256, 4) void conv_mfma_kernel(
        const float* __restrict__ x, const unsigned short* __restrict__ wp,
        const float* __restrict__ cb, float* __restrict__ pparts,
        float* __restrict__ spS, float* __restrict__ spQ) {
    __shared__ unsigned short xt[TSTG * CSTG];         // 288*48 B = 13824 B
    __shared__ float ps_s[NLOC * KP];                  // 768 B
    __shared__ float st_q[KP];                         // 192 B

    const int bx = blockIdx.x, b = blockIdx.y;
    const int w0   = (bx == 0) ? 0   : (bx == 1 ? 252 : (bx == 2 ? 500 : 752));
    const int oend = (bx == 0) ? 252 : (bx == 1 ? 500 : (bx == 2 ? 752 : WOUT));
    const int tid = threadIdx.x;
    const int wv = __builtin_amdgcn_readfirstlane(tid >> 6);
    const int lane = tid & 63;
    const size_t xb = (size_t)b * (CCH * TROW);

    for (int i = tid; i < NLOC * KP + KP; i += 256) {
        if (i < NLOC * KP) ps_s[i] = 0.0f;
        else st_q[i - NLOC * KP] = 0.0f;
    }

    // ---- stage x -> xt[t][c] bf16, row stride 48 B ----
    // 9 groups of 32 rows; lane = (row within group, c-half of 12)
    {
        const int r5 = lane & 31, h = lane >> 5;
#pragma unroll
        for (int it = 0; it < 3; ++it) {
            int idx = it * 4 + wv;                   // 0..11, active 0..8
            if (idx < 9) {
                int t_loc = idx * 32 + r5;
                int t_gl = w0 + t_loc;
                float v[12];
#pragma unroll
                for (int r = 0; r < 12; ++r) {
                    int c = h * 12 + r;
                    v[r] = (c < CCH && t_gl < TT) ? x[xb + (size_t)c * TROW + t_gl] : 0.0f;
                }
                unsigned u[6];
#pragma unroll
                for (int r = 0; r < 6; ++r) u[r] = cvt_pk_bf16(v[2 * r], v[2 * r + 1]);
                char* dst = (char*)xt + t_loc * ROWB + h * 24;
                *(uint2*)(dst)      = make_uint2(u[0], u[1]);
                *(uint2*)(dst + 8)  = make_uint2(u[2], u[3]);
                *(uint2*)(dst + 16) = make_uint2(u[4], u[5]);
            }
        }
    }
    __syncthreads();

    // ---- MFMA kk-loop: 19 K-steps of 32 over flattened (j,c), acc preloaded w/ bias ----
    const int m16 = lane & 15, g = lane >> 4;
    floatx4 acc[4][3];
#pragma unroll
    for (int nt = 0; nt < 3; ++nt) {
        int k = nt * 16 + m16;
        float bv = (k < KOUT) ? cb[k] : 0.0f;
#pragma unroll
        for (int mt = 0; mt < 4; ++mt) acc[mt][nt] = (floatx4){bv, bv, bv, bv};
    }

    const char* ap = (const char*)xt + (wv * 64 + m16) * ROWB + g * 16;
    const unsigned short* wpl = wp + m16 * 32 + g * 8;

    short8 bfr[3];
#pragma unroll
    for (int nt = 0; nt < 3; ++nt)
        bfr[nt] = *(const short8*)(wpl + nt * 16 * 32);

#pragma unroll 1
    for (int kk = 0; kk < FKK; ++kk) {
        short8 bnx[3];
        if (kk + 1 < FKK) {
            const unsigned short* wn = wpl + (kk + 1) * (KP * 32);
#pragma unroll
            for (int nt = 0; nt < 3; ++nt)
                bnx[nt] = *(const short8*)(wn + nt * 16 * 32);
        }
        short8 afr[4];
#pragma unroll
        for (int mt = 0; mt < 4; ++mt)
            afr[mt] = *(const short8*)(ap + mt * (16 * ROWB));
#pragma unroll
        for (int mt = 0; mt < 4; ++mt)
#pragma unroll
            for (int nt = 0; nt < 3; ++nt)
                acc[mt][nt] = __builtin_amdgcn_mfma_f32_16x16x32_bf16(
                    afr[mt], bfr[nt], acc[mt][nt], 0, 0, 0);
        ap += 64;                                   // next 32 flattened elems
#pragma unroll
        for (int nt = 0; nt < 3; ++nt) bfr[nt] = bnx[nt];
    }

    // ---- epilogue: ELU, ownership mask, pool segmented-reduce, BN sumsq ----
    const int win0 = w0 / POOLW;
    float qv[3] = {0.f, 0.f, 0.f};
#pragma unroll
    for (int mt = 0; mt < 4; ++mt) {
        const int wbase = w0 + wv * 64 + mt * 16 + g * 4;  // 4-aligned quad
        const int win = wbase / POOLW;                     // quad never straddles
#pragma unroll
        for (int nt = 0; nt < 3; ++nt) {
            const int k = nt * 16 + m16;
            const bool kok = (k < KOUT);
            float psum = 0.f;
#pragma unroll
            for (int r = 0; r < 4; ++r) {
                int w = wbase + r;
                float e = eluf(acc[mt][nt][r]);
                e = (kok && w < oend) ? e : 0.0f;          // exclusive ownership
                psum += e;
                qv[nt] = fmaf(e, e, qv[nt]);
            }
            // segmented reduce over the 4 row-groups (g), segments g-contiguous
            float o1 = __shfl_down(psum, 16); int w1 = __shfl_down(win, 16);
            if (lane < 48 && w1 == win) psum += o1;
            float o2 = __shfl_down(psum, 32); int w2 = __shfl_down(win, 32);
            if (lane < 32 && w2 == win) psum += o2;
            int wu = __shfl_up(win, 16);
            if (g == 0 || wu != win)
                atomicAdd(&ps_s[(win - win0) * KP + k], psum);
        }
    }
#pragma unroll
    for (int nt = 0; nt < 3; ++nt) {
        float q = qv[nt];
        q += __shfl_xor(q, 16);
        q += __shfl_xor(q, 32);
        if (g == 0) atomicAdd(&st_q[nt * 16 + m16], q);
    }
    __syncthreads();

    const int blk = b * NWB + bx;
    if (tid < KOUT) {
        // stats sum = sum of all owned pool slots (incl. pseudo-windows 9,10)
        float s = ps_s[tid] + ps_s[KP + tid] + ps_s[2 * KP + tid] + ps_s[3 * KP + tid];
        spS[(size_t)tid * NBLK + blk] = s;               // transposed: coalesced reduce
        spQ[(size_t)tid * NBLK + blk] = st_q[tid];
    }
    if (tid < NLOC * KOUT) {
        int wl = tid / KOUT, k = tid - wl * KOUT;
        pparts[((size_t)blk * NLOC + wl) * KOUT + k] = ps_s[wl * KP + k];
    }
}

// Reduce per-block stat partials -> BN scale/shift per k. grid KOUT.
__global__ __launch_bounds__(256) void bn_stats_kernel(
        const float* __restrict__ spS, const float* __restrict__ spQ,
        const float* __restrict__ gamma, const float* __restrict__ beta,
        float* __restrict__ scale, float* __restrict__ shift) {
    const int k = blockIdx.x;
    float s = 0.0f, q = 0.0f;
    for (int r = threadIdx.x; r < NBLK; r += 256) {
        s += spS[(size_t)k * NBLK + r];
        q += spQ[(size_t)k * NBLK + r];
    }
#pragma unroll
    for (int m = 32; m; m >>= 1) {
        s += __shfl_xor(s, m, 64);
        q += __shfl_xor(q, m, 64);
    }
    __shared__ float rs[4], rq[4];
    const int wid = threadIdx.x >> 6, lane = threadIdx.x & 63;
    if (lane == 0) { rs[wid] = s; rq[wid] = q; }
    __syncthreads();
    if (threadIdx.x == 0) {
        s = rs[0] + rs[1] + rs[2] + rs[3];
        q = rq[0] + rq[1] + rq[2] + rq[3];
        const float N = (float)BATCH * (float)WOUT;
        float mean = s / N;
        float var = q / N - mean * mean;
        float sc = gamma[k] / sqrtf(var + 1e-5f);
        scale[k] = sc;
        shift[k] = beta[k] - mean * sc;
    }
}

// Subject decode + window-part merge + BN-affine fold + 360x4 matvec.
// Window->(block,slot) source tables packed as nibbles (win 0..8):
//   A: {0,1,2,5,6,8,9,10,13}  B: {15,15,4,15,15,7,15,12,15} (15 = none)
__global__ __launch_bounds__(64) void fc_kernel(
        const float* __restrict__ x, const float* __restrict__ pparts,
        const float* __restrict__ scale, const float* __restrict__ shift,
        const float* __restrict__ fcw, const float* __restrict__ fcb,
        float* __restrict__ out) {
    const int b = blockIdx.x;
    const int lane = threadIdx.x;
    const float idv = x[(size_t)b * (CCH * TROW) + TT];   // x[b, 0, -1]
    const int sid = (int)(idv * 1e-6f + 0.5f) - 1;
    const float* W = fcw + (size_t)sid * (FEAT * NOUT);
    const float* base = pparts + (size_t)b * (NWB * NLOC * KOUT);
    const unsigned long long TA = 0xDA9865210ULL;
    const unsigned long long TB = 0xFCF7FF4FFULL;
    float a0 = 0, a1 = 0, a2 = 0, a3 = 0;
    for (int f = lane; f < FEAT; f += 64) {
        int k = f / NWIN, win = f - k * NWIN;
        unsigned sa = (unsigned)(TA >> (4 * win)) & 15u;
        unsigned sb = (unsigned)(TB >> (4 * win)) & 15u;
        float p = base[sa * KOUT + k];
        if (sb != 15u) p += base[sb * KOUT + k];
        float feat = fmaf(p * 0.01f, scale[k], shift[k]);
        a0 = fmaf(feat, W[f * 4 + 0], a0);
        a1 = fmaf(feat, W[f * 4 + 1], a1);
        a2 = fmaf(feat, W[f * 4 + 2], a2);
        a3 = fmaf(feat, W[f * 4 + 3], a3);
    }
#pragma unroll
    for (int m = 32; m; m >>= 1) {
        a0 += __shfl_xor(a0, m, 64);
        a1 += __shfl_xor(a1, m, 64);
        a2 += __shfl_xor(a2, m, 64);
        a3 += __shfl_xor(a3, m, 64);
    }
    if (lane == 0) {
        out[b * 4 + 0] = a0 + fcb[sid * 4 + 0];
        out[b * 4 + 1] = a1 + fcb[sid * 4 + 1];
        out[b * 4 + 2] = a2 + fcb[sid * 4 + 2];
        out[b * 4 + 3] = a3 + fcb[sid * 4 + 3];
    }
}

extern "C" void kernel_launch(void* const* d_in, const int* in_sizes, int n_in,
                              void* d_out, int out_size, void* d_ws, size_t ws_size,
                              hipStream_t stream) {
    const float* x     = (const float*)d_in[0];
    const float* cw    = (const float*)d_in[1];
    const float* cb    = (const float*)d_in[2];
    const float* gamma = (const float*)d_in[3];
    const float* beta  = (const float*)d_in[4];
    const float* fcw   = (const float*)d_in[5];
    const float* fcb   = (const float*)d_in[6];
    float* out = (float*)d_out;

    // workspace layout (no memset needed: every slot is plain-stored):
    //   pparts: NBLK*NLOC*KOUT f32 (pool-window partials)   10.49 MB
    //   spS/spQ: KOUT*NBLK f32 each (BN partials, transposed) 5.24 MB
    //   scale/shift: KOUT f32 each; wp: FKK*KP*32 bf16        58.4 KB
    float* pparts = (float*)d_ws;
    float* spS    = pparts + (size_t)NBLK * NLOC * KOUT;
    float* spQ    = spS + (size_t)KOUT * NBLK;
    float* scale  = spQ + (size_t)KOUT * NBLK;
    float* shift  = scale + KOUT;
    unsigned short* wpck = (unsigned short*)(shift + KOUT);

    pack_w_kernel<<<(FKK * KP * 32 + 255) / 256, 256, 0, stream>>>(cw, wpck);
    conv_mfma_kernel<<<dim3(NWB, BATCH), 256, 0, stream>>>(x, wpck, cb, pparts, spS, spQ);
    bn_stats_kernel<<<KOUT, 256, 0, stream>>>(spS, spQ, gamma, beta, scale, shift);
    fc_kernel<<<BATCH, 64, 0, stream>>>(x, pparts, scale, shift, fcw, fcb, out);
}

// Round 2
// 307.040 us; speedup vs baseline: 1.4093x; 1.1307x over previous
//
#include <hip/hip_runtime.h>

// Problem constants
#define BATCH 4096
#define CCH   22
#define TT    1001   // usable time samples (row length 1002; last elem = subject id)
#define TROW  1002
#define KOUT  40
#define KSZ   25
#define WOUT  977    // 1001 - 25 + 1
#define POOLW 100
#define NWIN  9
#define FEAT  360
#define NOUT  4

// Conv-MFMA tiling: 2 blocks along w, 512 computed w each, exclusive ownership
//   block 0: computes [0,512),   owns [0,500)    -> pool wins 0..4  (win0=0)
//   block 1: computes [488,1000) owns [500,977)  -> pool wins 5..8 + pseudo 9,10 (win0=4)
// Every pool window has exactly ONE owning block (split at w=500, a POOLW edge).
#define WBLK  512
#define NWB   2
#define NBLK  (BATCH * NWB)    // 8192
//
// im2col-by-stride: LDS x-tile is [t][c] bf16 with row stride EXACTLY CSTG=24
// elements (48 B). Flattened reduction index f = j*24 + c is LINEAR in LDS
// (byte = w*48 + 2*f), so MFMA A-fragments are contiguous b128 reads crossing
// tap boundaries. K-steps: ceil(25*24/32) = 19. Pads (c in {22,23}, f >= 600)
// are neutralized by zeroed WEIGHTS; A may read arbitrary finite staged data.
#define CSTG  24               // padded channels (row = 48 B, 16B-aligned b128)
#define ROWB  48               // LDS row stride bytes
#define TSTG  544              // rows staged (need 537 = 512 + 25); 17 groups of 32
#define FKK   19               // MFMA K-steps of 32 over flattened (j,c)
#define KP    48               // k_out padded to 3 MFMA n-tiles
#define NLOC  7                // pool-window slots per block (wins win0..win0+6)
#define NMT   8                // m-tiles per wave (wave covers 128 w)

typedef __attribute__((ext_vector_type(8))) short short8;
typedef __attribute__((ext_vector_type(4))) float floatx4;

__device__ __forceinline__ unsigned short f2bf(float f) {
    unsigned u = __float_as_uint(f);
    u += 0x7fff + ((u >> 16) & 1);          // round-to-nearest-even
    return (unsigned short)(u >> 16);
}
// HW packed f32->bf16 RNE convert (same rounding as f2bf, 1 instr for 2 vals)
__device__ __forceinline__ unsigned cvt_pk_bf16(float a, float b) {
    unsigned r;
    asm("v_cvt_pk_bf16_f32 %0, %1, %2" : "=v"(r) : "v"(a), "v"(b));
    return r;
}
__device__ __forceinline__ float eluf(float v) {
    return v > 0.0f ? v : __expf(v) - 1.0f;
}

// Pack conv weights into MFMA B-operand layout over the flattened reduction:
// wp[kk][n=0..47][e=0..31] bf16, where f = kk*32+e, j = f/24, c = f%24.
__global__ __launch_bounds__(256) void pack_w_kernel(const float* __restrict__ cw,
                                                     unsigned short* __restrict__ wp) {
    int i = blockIdx.x * 256 + threadIdx.x;      // over FKK*KP*32 = 29184
    if (i >= FKK * KP * 32) return;
    int e = i & 31;
    int n = (i >> 5) % KP;
    int kk = i / (KP * 32);
    int f = kk * 32 + e;
    int j = f / CSTG, c = f - j * CSTG;
    float v = (n < KOUT && c < CCH && j < KSZ) ? cw[(n * CCH + c) * KSZ + j] : 0.0f;
    wp[i] = f2bf(v);
}

// Conv(bf16 MFMA) + bias + ELU + owned pool-window sums + owned BN partials.
// grid (NWB, BATCH), block 256 = 4 waves; wave wv owns 128 w's (8 m-tiles).
__global__ __launch_bounds__(256, 3) void conv_mfma_kernel(
        const float* __restrict__ x, const unsigned short* __restrict__ wp,
        const float* __restrict__ cb, float* __restrict__ pparts,
        float* __restrict__ spS, float* __restrict__ spQ) {
    __shared__ unsigned short xt[TSTG * CSTG];         // 544*48 B = 26112 B
    __shared__ float ps_s[NLOC * KP];                  // 1344 B
    __shared__ float st_q[KP];                         // 192 B

    const int bx = blockIdx.x, b = blockIdx.y;
    const int w0     = bx ? 488 : 0;     // first computed w
    const int ostart = bx ? 500 : 0;     // ownership [ostart, oend)
    const int oend   = bx ? WOUT : 500;
    const int win0   = bx ? 4 : 0;       // slot s holds pool window win0+s
    const int tid = threadIdx.x;
    const int wv = __builtin_amdgcn_readfirstlane(tid >> 6);
    const int lane = tid & 63;
    const size_t xb = (size_t)b * (CCH * TROW);

    for (int i = tid; i < NLOC * KP + KP; i += 256) {
        if (i < NLOC * KP) ps_s[i] = 0.0f;
        else st_q[i - NLOC * KP] = 0.0f;
    }

    // ---- stage x -> xt[t][c] bf16, row stride 48 B ----
    // 17 groups of 32 rows; lane = (row-in-group r5, c-half h of 12 channels)
    {
        const int r5 = lane & 31, h = lane >> 5;
#pragma unroll
        for (int it = 0; it < 5; ++it) {
            int idx = it * 4 + wv;                   // 0..19, active 0..16
            if (idx < 17) {
                int t_loc = idx * 32 + r5;
                int t_gl = w0 + t_loc;
                float v[12];
#pragma unroll
                for (int r = 0; r < 12; ++r) {
                    int c = h * 12 + r;
                    v[r] = (c < CCH && t_gl < TT) ? x[xb + (size_t)c * TROW + t_gl] : 0.0f;
                }
                unsigned u[6];
#pragma unroll
                for (int r = 0; r < 6; ++r) u[r] = cvt_pk_bf16(v[2 * r], v[2 * r + 1]);
                char* dst = (char*)xt + t_loc * ROWB + h * 24;
                *(uint2*)(dst)      = make_uint2(u[0], u[1]);
                *(uint2*)(dst + 8)  = make_uint2(u[2], u[3]);
                *(uint2*)(dst + 16) = make_uint2(u[4], u[5]);
            }
        }
    }
    __syncthreads();

    // ---- MFMA kk-loop: 19 K-steps of 32 over flattened (j,c), acc preloaded w/ bias ----
    const int m16 = lane & 15, g = lane >> 4;
    floatx4 acc[NMT][3];
#pragma unroll
    for (int nt = 0; nt < 3; ++nt) {
        int k = nt * 16 + m16;
        float bv = (k < KOUT) ? cb[k] : 0.0f;
#pragma unroll
        for (int mt = 0; mt < NMT; ++mt) acc[mt][nt] = (floatx4){bv, bv, bv, bv};
    }

    const char* ap = (const char*)xt + (wv * 128 + m16) * ROWB + g * 16;
    const unsigned short* wpl = wp + m16 * 32 + g * 8;

    short8 bfr[3];
#pragma unroll
    for (int nt = 0; nt < 3; ++nt)
        bfr[nt] = *(const short8*)(wpl + nt * 16 * 32);

#pragma unroll 1
    for (int kk = 0; kk < FKK; ++kk) {
        short8 bnx[3];
        if (kk + 1 < FKK) {
            const unsigned short* wn = wpl + (kk + 1) * (KP * 32);
#pragma unroll
            for (int nt = 0; nt < 3; ++nt)
                bnx[nt] = *(const short8*)(wn + nt * 16 * 32);
        }
        // A-frags in two groups of 4 (keeps live regs ~16, 12-MFMA train each)
#pragma unroll
        for (int half = 0; half < 2; ++half) {
            short8 afr[4];
#pragma unroll
            for (int q = 0; q < 4; ++q)
                afr[q] = *(const short8*)(ap + (half * 4 + q) * (16 * ROWB));
#pragma unroll
            for (int q = 0; q < 4; ++q)
#pragma unroll
                for (int nt = 0; nt < 3; ++nt)
                    acc[half * 4 + q][nt] = __builtin_amdgcn_mfma_f32_16x16x32_bf16(
                        afr[q], bfr[nt], acc[half * 4 + q][nt], 0, 0, 0);
        }
        ap += 64;                                   // next 32 flattened elems
#pragma unroll
        for (int nt = 0; nt < 3; ++nt) bfr[nt] = bnx[nt];
    }

    // ---- epilogue: ELU, ownership mask, pool segmented-reduce, BN sumsq ----
    float qv[3] = {0.f, 0.f, 0.f};
#pragma unroll
    for (int mt = 0; mt < NMT; ++mt) {
        const int wbase = w0 + wv * 128 + mt * 16 + g * 4;  // 4-aligned quad
        const int win = wbase / POOLW;                      // quad never straddles
#pragma unroll
        for (int nt = 0; nt < 3; ++nt) {
            const int k = nt * 16 + m16;
            const bool kok = (k < KOUT);
            float psum = 0.f;
#pragma unroll
            for (int r = 0; r < 4; ++r) {
                int w = wbase + r;
                float e = eluf(acc[mt][nt][r]);
                e = (kok && w >= ostart && w < oend) ? e : 0.0f;  // exclusive ownership
                psum += e;
                qv[nt] = fmaf(e, e, qv[nt]);
            }
            // segmented reduce over the 4 row-groups (g), segments g-contiguous
            float o1 = __shfl_down(psum, 16); int w1 = __shfl_down(win, 16);
            if (lane < 48 && w1 == win) psum += o1;
            float o2 = __shfl_down(psum, 32); int w2 = __shfl_down(win, 32);
            if (lane < 32 && w2 == win) psum += o2;
            int wu = __shfl_up(win, 16);
            if (g == 0 || wu != win)
                atomicAdd(&ps_s[(win - win0) * KP + k], psum);
        }
    }
#pragma unroll
    for (int nt = 0; nt < 3; ++nt) {
        float q = qv[nt];
        q += __shfl_xor(q, 16);
        q += __shfl_xor(q, 32);
        if (g == 0) atomicAdd(&st_q[nt * 16 + m16], q);
    }
    __syncthreads();

    const int blk = b * NWB + bx;
    if (tid < KOUT) {
        // stats sum = sum of all owned pool slots (incl. pseudo/zero windows)
        float s = 0.0f;
#pragma unroll
        for (int wl = 0; wl < NLOC; ++wl) s += ps_s[wl * KP + tid];
        spS[(size_t)tid * NBLK + blk] = s;               // transposed: coalesced reduce
        spQ[(size_t)tid * NBLK + blk] = st_q[tid];
    }
    for (int i = tid; i < NLOC * KOUT; i += 256) {
        int wl = i / KOUT, k = i - wl * KOUT;
        pparts[((size_t)blk * NLOC + wl) * KOUT + k] = ps_s[wl * KP + k];
    }
}

// Reduce per-block stat partials -> BN scale/shift per k. grid KOUT.
__global__ __launch_bounds__(256) void bn_stats_kernel(
        const float* __restrict__ spS, const float* __restrict__ spQ,
        const float* __restrict__ gamma, const float* __restrict__ beta,
        float* __restrict__ scale, float* __restrict__ shift) {
    const int k = blockIdx.x;
    float s = 0.0f, q = 0.0f;
    for (int r = threadIdx.x; r < NBLK; r += 256) {
        s += spS[(size_t)k * NBLK + r];
        q += spQ[(size_t)k * NBLK + r];
    }
#pragma unroll
    for (int m = 32; m; m >>= 1) {
        s += __shfl_xor(s, m, 64);
        q += __shfl_xor(q, m, 64);
    }
    __shared__ float rs[4], rq[4];
    const int wid = threadIdx.x >> 6, lane = threadIdx.x & 63;
    if (lane == 0) { rs[wid] = s; rq[wid] = q; }
    __syncthreads();
    if (threadIdx.x == 0) {
        s = rs[0] + rs[1] + rs[2] + rs[3];
        q = rq[0] + rq[1] + rq[2] + rq[3];
        const float N = (float)BATCH * (float)WOUT;
        float mean = s / N;
        float var = q / N - mean * mean;
        float sc = gamma[k] / sqrtf(var + 1e-5f);
        scale[k] = sc;
        shift[k] = beta[k] - mean * sc;
    }
}

// Subject decode + BN-affine fold + 360x4 matvec.
// Each pool window has exactly one source slot:
//   win 0..4 -> block 0 slot win        (unit index win)
//   win 5..8 -> block 1 slot win-4      (unit index NLOC + win-4 = win+3)
__global__ __launch_bounds__(64) void fc_kernel(
        const float* __restrict__ x, const float* __restrict__ pparts,
        const float* __restrict__ scale, const float* __restrict__ shift,
        const float* __restrict__ fcw, const float* __restrict__ fcb,
        float* __restrict__ out) {
    const int b = blockIdx.x;
    const int lane = threadIdx.x;
    const float idv = x[(size_t)b * (CCH * TROW) + TT];   // x[b, 0, -1]
    const int sid = (int)(idv * 1e-6f + 0.5f) - 1;
    const float* W = fcw + (size_t)sid * (FEAT * NOUT);
    const float* base = pparts + (size_t)b * (NWB * NLOC * KOUT);
    float a0 = 0, a1 = 0, a2 = 0, a3 = 0;
    for (int f = lane; f < FEAT; f += 64) {
        int k = f / NWIN, win = f - k * NWIN;
        int u = (win < 5) ? win : (win + 3);
        float p = base[u * KOUT + k];
        float feat = fmaf(p * 0.01f, scale[k], shift[k]);
        a0 = fmaf(feat, W[f * 4 + 0], a0);
        a1 = fmaf(feat, W[f * 4 + 1], a1);
        a2 = fmaf(feat, W[f * 4 + 2], a2);
        a3 = fmaf(feat, W[f * 4 + 3], a3);
    }
#pragma unroll
    for (int m = 32; m; m >>= 1) {
        a0 += __shfl_xor(a0, m, 64);
        a1 += __shfl_xor(a1, m, 64);
        a2 += __shfl_xor(a2, m, 64);
        a3 += __shfl_xor(a3, m, 64);
    }
    if (lane == 0) {
        out[b * 4 + 0] = a0 + fcb[sid * 4 + 0];
        out[b * 4 + 1] = a1 + fcb[sid * 4 + 1];
        out[b * 4 + 2] = a2 + fcb[sid * 4 + 2];
        out[b * 4 + 3] = a3 + fcb[sid * 4 + 3];
    }
}

extern "C" void kernel_launch(void* const* d_in, const int* in_sizes, int n_in,
                              void* d_out, int out_size, void* d_ws, size_t ws_size,
                              hipStream_t stream) {
    const float* x     = (const float*)d_in[0];
    const float* cw    = (const float*)d_in[1];
    const float* cb    = (const float*)d_in[2];
    const float* gamma = (const float*)d_in[3];
    const float* beta  = (const float*)d_in[4];
    const float* fcw   = (const float*)d_in[5];
    const float* fcb   = (const float*)d_in[6];
    float* out = (float*)d_out;

    // workspace layout (no memset needed: every slot is plain-stored):
    //   pparts: NBLK*NLOC*KOUT f32 (pool-window partials)    9.17 MB
    //   spS/spQ: KOUT*NBLK f32 each (BN partials, transposed) 2.62 MB
    //   scale/shift: KOUT f32 each; wp: FKK*KP*32 bf16        58.4 KB
    float* pparts = (float*)d_ws;
    float* spS    = pparts + (size_t)NBLK * NLOC * KOUT;
    float* spQ    = spS + (size_t)KOUT * NBLK;
    float* scale  = spQ + (size_t)KOUT * NBLK;
    float* shift  = scale + KOUT;
    unsigned short* wpck = (unsigned short*)(shift + KOUT);

    pack_w_kernel<<<(FKK * KP * 32 + 255) / 256, 256, 0, stream>>>(cw, wpck);
    conv_mfma_kernel<<<dim3(NWB, BATCH), 256, 0, stream>>>(x, wpck, cb, pparts, spS, spQ);
    bn_stats_kernel<<<KOUT, 256, 0, stream>>>(spS, spQ, gamma, beta, scale, shift);
    fc_kernel<<<BATCH, 64, 0, stream>>>(x, pparts, scale, shift, fcw, fcb, out);
}